// Round 1
// baseline (471.389 us; speedup 1.0000x reference)
//
#include <hip/hip_runtime.h>
#include <hip/hip_bf16.h>
#include <stdint.h>

// ---------------------------------------------------------------------------
// CrossViewIPAttnProcessor on MI355X (gfx950)
// B=8, Lq=4096, D=1024, Dc=768, H=16, HD=64, text=77 keys, ip=4 keys
// Pipeline:
//   1) weights fp32->bf16
//   2) Xn[8][96][768]: rows 0..76 = LN(text), 80..83 = raw ip, rest 0
//   3) kv gemm: K_all[bh][96][64], Vt[bh][64][96] (zero-padded keys)
//   4) Q gemm (A fp32 reg-staged->bf16, B gload_lds), Q bf16 -> first half of d_out
//   5) attention (MFMA scores + wave-parallel softmax + MFMA PV) -> attn bf16 in ws
//   6) out gemm (both operands gload_lds) + bias -> d_out fp32
// ---------------------------------------------------------------------------

typedef __attribute__((ext_vector_type(8))) short short8;
typedef __attribute__((ext_vector_type(4))) float f32x4;

__device__ __forceinline__ ushort f2b(float f) {
  union { float f; uint32_t u; } v; v.f = f;
  uint32_t r = (v.u + 0x7fffu + ((v.u >> 16) & 1u)) >> 16;  // RNE bf16
  return (ushort)r;
}

__device__ __forceinline__ short8 pack2(float4 a, float4 b) {
  short8 r;
  r[0] = (short)f2b(a.x); r[1] = (short)f2b(a.y); r[2] = (short)f2b(a.z); r[3] = (short)f2b(a.w);
  r[4] = (short)f2b(b.x); r[5] = (short)f2b(b.y); r[6] = (short)f2b(b.z); r[7] = (short)f2b(b.w);
  return r;
}

#define GLD16(gp, lp) \
  __builtin_amdgcn_global_load_lds((const __attribute__((address_space(1))) uint32_t*)(gp), \
                                   (__attribute__((address_space(3))) uint32_t*)(lp), 16, 0, 0)

// --------------------------- 1) fp32 -> bf16 -------------------------------
__global__ void k_cvt(const float* __restrict__ src, ushort* __restrict__ dst, int n4) {
  int i = blockIdx.x * blockDim.x + threadIdx.x;
  if (i >= n4) return;
  float4 v = reinterpret_cast<const float4*>(src)[i];
  ushort4 o;
  o.x = f2b(v.x); o.y = f2b(v.y); o.z = f2b(v.z); o.w = f2b(v.w);
  reinterpret_cast<ushort4*>(dst)[i] = o;
}

// --------------------------- 2) Xn builder ---------------------------------
// grid (96, 8), 256 thr. tok<77: LN(text); 77..79: 0; 80..83: raw ip; 84..95: 0
__global__ __launch_bounds__(256) void k_build_xn(const float* __restrict__ enc,
                                                  const float* __restrict__ lnw,
                                                  const float* __restrict__ lnb,
                                                  ushort* __restrict__ xn) {
  const int Dc = 768;
  int tok = blockIdx.x, b = blockIdx.y, t = threadIdx.x;
  ushort* out = xn + ((size_t)b * 96 + tok) * Dc;
  bool padrow = (tok >= 84) || (tok >= 77 && tok < 80);
  if (padrow) { out[t] = 0; out[t + 256] = 0; out[t + 512] = 0; return; }
  const float* src = (tok < 77) ? enc + ((size_t)b * 81 + tok) * Dc
                                : enc + ((size_t)b * 81 + 77 + (tok - 80)) * Dc;
  float x0 = src[t], x1 = src[t + 256], x2 = src[t + 512];
  if (tok >= 80) { out[t] = f2b(x0); out[t + 256] = f2b(x1); out[t + 512] = f2b(x2); return; }
  float s = x0 + x1 + x2, q = x0 * x0 + x1 * x1 + x2 * x2;
  for (int m = 32; m; m >>= 1) { s += __shfl_xor(s, m, 64); q += __shfl_xor(q, m, 64); }
  __shared__ float rs[4], rq[4];
  int w = t >> 6;
  if ((t & 63) == 0) { rs[w] = s; rq[w] = q; }
  __syncthreads();
  s = rs[0] + rs[1] + rs[2] + rs[3];
  q = rq[0] + rq[1] + rq[2] + rq[3];
  float mean = s * (1.0f / 768.0f);
  float var = q * (1.0f / 768.0f) - mean * mean;
  float rstd = rsqrtf(var + 1e-5f);
  out[t]       = f2b((x0 - mean) * rstd * lnw[t]       + lnb[t]);
  out[t + 256] = f2b((x1 - mean) * rstd * lnw[t + 256] + lnb[t + 256]);
  out[t + 512] = f2b((x2 - mean) * rstd * lnw[t + 512] + lnb[t + 512]);
}

// --------------------------- 3) K/V projection -----------------------------
// C[96][1024] = Xn[96][768] @ W^T, tokens>=80 use W_ip. grid (4 ntiles, 8 b).
// mode 0: K_all[b][h][tok][dd]; mode 1: Vt[b][h][dd][tok]
__global__ __launch_bounds__(256) void k_kv(const ushort* __restrict__ xn,
                                            const ushort* __restrict__ wb,
                                            const ushort* __restrict__ wipb,
                                            ushort* __restrict__ out, int mode) {
  int n0 = blockIdx.x * 256, b = blockIdx.y;
  int t = threadIdx.x, w = t >> 6, l = t & 63, lo = l & 15, hi = l >> 4;
  __shared__ alignas(16) ushort Xs[96 * 32];
  __shared__ alignas(16) ushort Ws[256 * 32];
  __shared__ alignas(16) ushort Wip[256 * 32];
  f32x4 acc[6][4];
  f32x4 zf = {0.f, 0.f, 0.f, 0.f};
  for (int i = 0; i < 6; i++) for (int j = 0; j < 4; j++) acc[i][j] = zf;
  const ushort* xb = xn + (size_t)b * 96 * 768;
  for (int k0 = 0; k0 < 768; k0 += 32) {
    __syncthreads();
    for (int i = t; i < 96 * 16; i += 256) {
      int row = i >> 4, p = i & 15;
      reinterpret_cast<uint32_t*>(Xs)[i] =
          *reinterpret_cast<const uint32_t*>(xb + row * 768 + k0 + p * 2);
    }
    for (int i = t; i < 256 * 16; i += 256) {
      int row = i >> 4, p = i & 15;
      reinterpret_cast<uint32_t*>(Ws)[i] =
          *reinterpret_cast<const uint32_t*>(wb + (size_t)(n0 + row) * 768 + k0 + p * 2);
      reinterpret_cast<uint32_t*>(Wip)[i] =
          *reinterpret_cast<const uint32_t*>(wipb + (size_t)(n0 + row) * 768 + k0 + p * 2);
    }
    __syncthreads();
    short8 a[6], bb[4], bip[4];
    for (int mi = 0; mi < 6; mi++)
      a[mi] = *reinterpret_cast<const short8*>(Xs + (mi * 16 + lo) * 32 + hi * 8);
    for (int ni = 0; ni < 4; ni++) {
      bb[ni]  = *reinterpret_cast<const short8*>(Ws  + (w * 64 + ni * 16 + lo) * 32 + hi * 8);
      bip[ni] = *reinterpret_cast<const short8*>(Wip + (w * 64 + ni * 16 + lo) * 32 + hi * 8);
    }
    for (int ni = 0; ni < 4; ni++) {
      for (int mi = 0; mi < 5; mi++)
        acc[mi][ni] = __builtin_amdgcn_mfma_f32_16x16x32_bf16(a[mi], bb[ni], acc[mi][ni], 0, 0, 0);
      acc[5][ni] = __builtin_amdgcn_mfma_f32_16x16x32_bf16(a[5], bip[ni], acc[5][ni], 0, 0, 0);
    }
  }
  for (int mi = 0; mi < 6; mi++)
    for (int ni = 0; ni < 4; ni++) {
      int col = n0 + w * 64 + ni * 16 + lo;
      int h = col >> 6, dd = col & 63;
      for (int j = 0; j < 4; j++) {
        int tok = mi * 16 + hi * 4 + j;
        ushort v = f2b(acc[mi][ni][j]);
        if (mode == 0) out[(((size_t)b * 16 + h) * 96 + tok) * 64 + dd] = v;
        else           out[(((size_t)b * 16 + h) * 64 + dd) * 96 + tok] = v;
      }
    }
}

// --------------------------- 4) Q projection GEMM --------------------------
// C[32768][1024] bf16 = A[32768][1024] fp32 @ Bw[1024][1024]^T bf16
// 1-D grid 2048, XCD-chunked swizzle; 128x128 tile, BK=32, 4 waves 2x2.
__global__ __launch_bounds__(256) void k_qgemm(const float* __restrict__ A,
                                               const ushort* __restrict__ Bw,
                                               ushort* __restrict__ C) {
  const int K = 1024;
  int wg = blockIdx.x;
  int nid = (wg & 7) * 256 + (wg >> 3);   // XCD-chunked: each XCD owns 32 m-tiles
  int m0 = (nid >> 3) * 128, n0 = (nid & 7) * 128;
  int t = threadIdx.x, w = t >> 6, l = t & 63, lo = l & 15, hi = l >> 4;
  int wm = w >> 1, wn = w & 1;
  __shared__ alignas(16) ushort As[128 * 32];
  __shared__ alignas(16) ushort Bs[128 * 32];
  f32x4 acc[4][4];
  f32x4 zf = {0.f, 0.f, 0.f, 0.f};
  for (int i = 0; i < 4; i++) for (int j = 0; j < 4; j++) acc[i][j] = zf;
  int ar = t >> 2, ac = (t & 3) * 8;
  const float* ga = A + (size_t)(m0 + ar) * K + ac;
  for (int k0 = 0; k0 < K; k0 += 32) {
    float4 v0 = *reinterpret_cast<const float4*>(ga + k0);
    float4 v1 = *reinterpret_cast<const float4*>(ga + k0 + 4);
    float4 v2 = *reinterpret_cast<const float4*>(ga + (size_t)64 * K + k0);
    float4 v3 = *reinterpret_cast<const float4*>(ga + (size_t)64 * K + k0 + 4);
    __syncthreads();
    *reinterpret_cast<short8*>(As + ar * 32 + ac) = pack2(v0, v1);          // byte t*16: linear
    *reinterpret_cast<short8*>(As + (64 + ar) * 32 + ac) = pack2(v2, v3);
    for (int i = 0; i < 2; i++) {
      int unit = (i * 4 + w) * 64 + l;
      int row = unit >> 2, c8 = (unit & 3) * 8;
      GLD16(Bw + (size_t)(n0 + row) * K + k0 + c8, Bs + (i * 4 + w) * 512);
    }
    __syncthreads();
    short8 af[4], bf_[4];
    for (int mi = 0; mi < 4; mi++)
      af[mi] = *reinterpret_cast<const short8*>(As + (wm * 64 + mi * 16 + lo) * 32 + hi * 8);
    for (int ni = 0; ni < 4; ni++)
      bf_[ni] = *reinterpret_cast<const short8*>(Bs + (wn * 64 + ni * 16 + lo) * 32 + hi * 8);
    for (int mi = 0; mi < 4; mi++)
      for (int ni = 0; ni < 4; ni++)
        acc[mi][ni] = __builtin_amdgcn_mfma_f32_16x16x32_bf16(af[mi], bf_[ni], acc[mi][ni], 0, 0, 0);
  }
  for (int mi = 0; mi < 4; mi++)
    for (int ni = 0; ni < 4; ni++)
      for (int j = 0; j < 4; j++) {
        int r = m0 + wm * 64 + mi * 16 + hi * 4 + j;
        int c = n0 + wn * 64 + ni * 16 + lo;
        C[(size_t)r * 1024 + c] = f2b(acc[mi][ni][j]);
      }
}

// --------------------------- 5) attention ----------------------------------
// grid (32 q-tiles, 128 bh). Per wave: 32 q-rows. Keys merged 0..95:
//   0..76 text (softmax A), 80..83 ip (softmax B), rest zero/masked.
__global__ __launch_bounds__(256) void k_attn(const ushort* __restrict__ Q,
                                              const ushort* __restrict__ Kall,
                                              const ushort* __restrict__ Vt,
                                              ushort* __restrict__ O) {
  int q0 = blockIdx.x * 128, bh = blockIdx.y;
  int b = bh >> 4, h = bh & 15;
  int t = threadIdx.x, w = t >> 6, l = t & 63, lo = l & 15, hi = l >> 4;
  __shared__ alignas(16) ushort P[4][32 * 104];  // per-wave P tile, padded stride
  const ushort* Qb = Q + ((size_t)b * 4096 + q0 + w * 32) * 1024 + h * 64;
  short8 qf[2][2];
  for (int mi = 0; mi < 2; mi++)
    for (int ks = 0; ks < 2; ks++)
      qf[mi][ks] = *reinterpret_cast<const short8*>(Qb + (size_t)(mi * 16 + lo) * 1024 + ks * 32 + hi * 8);
  const ushort* Kb = Kall + (size_t)bh * 96 * 64;
  f32x4 s[2][6];
  f32x4 zf = {0.f, 0.f, 0.f, 0.f};
  for (int i = 0; i < 2; i++) for (int j = 0; j < 6; j++) s[i][j] = zf;
  for (int ni = 0; ni < 6; ni++)
    for (int ks = 0; ks < 2; ks++) {
      short8 kf = *reinterpret_cast<const short8*>(Kb + (ni * 16 + lo) * 64 + ks * 32 + hi * 8);
      for (int mi = 0; mi < 2; mi++)
        s[mi][ni] = __builtin_amdgcn_mfma_f32_16x16x32_bf16(qf[mi][ks], kf, s[mi][ni], 0, 0, 0);
    }
  const float SC = 0.125f * 1.44269504088896340736f;  // 1/sqrt(64) * log2(e)
  for (int mi = 0; mi < 2; mi++)
    for (int j = 0; j < 4; j++) {
      float pb[5];
      float mb = -1e30f;
      for (int ni = 0; ni < 5; ni++) {
        int c = ni * 16 + lo;
        float v = s[mi][ni][j] * SC;
        pb[ni] = v;
        if (c < 77) mb = fmaxf(mb, v);
      }
      mb = fmaxf(mb, __shfl_xor(mb, 1, 64));
      mb = fmaxf(mb, __shfl_xor(mb, 2, 64));
      mb = fmaxf(mb, __shfl_xor(mb, 4, 64));
      mb = fmaxf(mb, __shfl_xor(mb, 8, 64));
      float sb = 0.f;
      for (int ni = 0; ni < 5; ni++) {
        int c = ni * 16 + lo;
        float p = (c < 77) ? exp2f(pb[ni] - mb) : 0.f;
        pb[ni] = p; sb += p;
      }
      sb += __shfl_xor(sb, 1, 64); sb += __shfl_xor(sb, 2, 64);
      sb += __shfl_xor(sb, 4, 64); sb += __shfl_xor(sb, 8, 64);
      float rb = 1.0f / sb;
      // ip softmax (cols 80..83 -> ni=5 lanes lo<4)
      float vip = s[mi][5][j] * SC;
      bool val = lo < 4;
      float mip = val ? vip : -1e30f;
      mip = fmaxf(mip, __shfl_xor(mip, 1, 64));
      mip = fmaxf(mip, __shfl_xor(mip, 2, 64));
      mip = fmaxf(mip, __shfl_xor(mip, 4, 64));
      mip = fmaxf(mip, __shfl_xor(mip, 8, 64));
      float pi = val ? exp2f(vip - mip) : 0.f;
      float si = pi;
      si += __shfl_xor(si, 1, 64); si += __shfl_xor(si, 2, 64);
      si += __shfl_xor(si, 4, 64); si += __shfl_xor(si, 8, 64);
      float ri = 1.0f / si;
      int row = mi * 16 + hi * 4 + j;
      ushort* pr = &P[w][row * 104];
      for (int ni = 0; ni < 5; ni++) pr[ni * 16 + lo] = f2b(pb[ni] * rb);
      pr[80 + lo] = f2b(pi * ri);  // zero for lo>=4
    }
  __syncthreads();
  f32x4 o[2][4];
  for (int i = 0; i < 2; i++) for (int j = 0; j < 4; j++) o[i][j] = zf;
  const ushort* Vb = Vt + (size_t)bh * 64 * 96;
  for (int kk = 0; kk < 3; kk++) {
    short8 pf[2];
    for (int mi = 0; mi < 2; mi++)
      pf[mi] = *reinterpret_cast<const short8*>(&P[w][(mi * 16 + lo) * 104 + kk * 32 + hi * 8]);
    for (int dn = 0; dn < 4; dn++) {
      short8 vf = *reinterpret_cast<const short8*>(Vb + (dn * 16 + lo) * 96 + kk * 32 + hi * 8);
      for (int mi = 0; mi < 2; mi++)
        o[mi][dn] = __builtin_amdgcn_mfma_f32_16x16x32_bf16(pf[mi], vf, o[mi][dn], 0, 0, 0);
    }
  }
  ushort* Ob = O + ((size_t)b * 4096 + q0 + w * 32) * 1024 + h * 64;
  for (int mi = 0; mi < 2; mi++)
    for (int dn = 0; dn < 4; dn++)
      for (int j = 0; j < 4; j++)
        Ob[(size_t)(mi * 16 + hi * 4 + j) * 1024 + dn * 16 + lo] = f2b(o[mi][dn][j]);
}

// --------------------------- 6) output GEMM + bias -------------------------
__global__ __launch_bounds__(256) void k_ogemm(const ushort* __restrict__ A,
                                               const ushort* __restrict__ Bw,
                                               const float* __restrict__ bias,
                                               float* __restrict__ C) {
  const int K = 1024;
  int wg = blockIdx.x;
  int nid = (wg & 7) * 256 + (wg >> 3);
  int m0 = (nid >> 3) * 128, n0 = (nid & 7) * 128;
  int t = threadIdx.x, w = t >> 6, l = t & 63, lo = l & 15, hi = l >> 4;
  int wm = w >> 1, wn = w & 1;
  __shared__ alignas(16) ushort As[128 * 32];
  __shared__ alignas(16) ushort Bs[128 * 32];
  f32x4 acc[4][4];
  f32x4 zf = {0.f, 0.f, 0.f, 0.f};
  for (int i = 0; i < 4; i++) for (int j = 0; j < 4; j++) acc[i][j] = zf;
  for (int k0 = 0; k0 < K; k0 += 32) {
    __syncthreads();
    for (int i = 0; i < 2; i++) {
      int unit = (i * 4 + w) * 64 + l;
      int row = unit >> 2, c8 = (unit & 3) * 8;
      GLD16(A  + (size_t)(m0 + row) * K + k0 + c8, As + (i * 4 + w) * 512);
      GLD16(Bw + (size_t)(n0 + row) * K + k0 + c8, Bs + (i * 4 + w) * 512);
    }
    __syncthreads();
    short8 af[4], bf_[4];
    for (int mi = 0; mi < 4; mi++)
      af[mi] = *reinterpret_cast<const short8*>(As + (wm * 64 + mi * 16 + lo) * 32 + hi * 8);
    for (int ni = 0; ni < 4; ni++)
      bf_[ni] = *reinterpret_cast<const short8*>(Bs + (wn * 64 + ni * 16 + lo) * 32 + hi * 8);
    for (int mi = 0; mi < 4; mi++)
      for (int ni = 0; ni < 4; ni++)
        acc[mi][ni] = __builtin_amdgcn_mfma_f32_16x16x32_bf16(af[mi], bf_[ni], acc[mi][ni], 0, 0, 0);
  }
  for (int mi = 0; mi < 4; mi++)
    for (int ni = 0; ni < 4; ni++) {
      int c = n0 + wn * 64 + ni * 16 + lo;
      float bv = bias[c];
      for (int j = 0; j < 4; j++) {
        int r = m0 + wm * 64 + mi * 16 + hi * 4 + j;
        C[(size_t)r * 1024 + c] = acc[mi][ni][j] + bv;
      }
    }
}

// ---------------------------------------------------------------------------
extern "C" void kernel_launch(void* const* d_in, const int* in_sizes, int n_in,
                              void* d_out, int out_size, void* d_ws, size_t ws_size,
                              hipStream_t stream) {
  const float* hs   = (const float*)d_in[0];
  const float* enc  = (const float*)d_in[1];
  const float* Wq   = (const float*)d_in[2];
  const float* Wk   = (const float*)d_in[3];
  const float* Wv   = (const float*)d_in[4];
  const float* Wkip = (const float*)d_in[5];
  const float* Wvip = (const float*)d_in[6];
  const float* Wo   = (const float*)d_in[7];
  const float* bo   = (const float*)d_in[8];
  const float* lnw  = (const float*)d_in[9];
  const float* lnb  = (const float*)d_in[10];
  float* out = (float*)d_out;
  ushort* Qbuf = (ushort*)d_out;  // bf16 Q parked in first 64MB of the 128MB output

  ushort* p = (ushort*)d_ws;      // total ws use: ~82 MB
  ushort* attn    = p; p += (size_t)32768 * 1024;
  ushort* wq_bf   = p; p += (size_t)1024 * 1024;
  ushort* wo_bf   = p; p += (size_t)1024 * 1024;
  ushort* wk_bf   = p; p += (size_t)1024 * 768;
  ushort* wkip_bf = p; p += (size_t)1024 * 768;
  ushort* wv_bf   = p; p += (size_t)1024 * 768;
  ushort* wvip_bf = p; p += (size_t)1024 * 768;
  ushort* xn      = p; p += (size_t)8 * 96 * 768;
  ushort* kall    = p; p += (size_t)8 * 16 * 96 * 64;
  ushort* vtall   = p; p += (size_t)8 * 16 * 96 * 64;

  k_cvt<<<1024, 256, 0, stream>>>(Wq, wq_bf, 262144);
  k_cvt<<<1024, 256, 0, stream>>>(Wo, wo_bf, 262144);
  k_cvt<<<768, 256, 0, stream>>>(Wk, wk_bf, 196608);
  k_cvt<<<768, 256, 0, stream>>>(Wkip, wkip_bf, 196608);
  k_cvt<<<768, 256, 0, stream>>>(Wv, wv_bf, 196608);
  k_cvt<<<768, 256, 0, stream>>>(Wvip, wvip_bf, 196608);
  k_build_xn<<<dim3(96, 8), 256, 0, stream>>>(enc, lnw, lnb, xn);
  k_kv<<<dim3(4, 8), 256, 0, stream>>>(xn, wk_bf, wkip_bf, kall, 0);
  k_kv<<<dim3(4, 8), 256, 0, stream>>>(xn, wv_bf, wvip_bf, vtall, 1);
  k_qgemm<<<2048, 256, 0, stream>>>(hs, wq_bf, Qbuf);
  k_attn<<<dim3(32, 128), 256, 0, stream>>>(Qbuf, kall, vtall, attn);
  k_ogemm<<<2048, 256, 0, stream>>>(attn, wo_bf, bo, out);
}

// Round 2
// 447.083 us; speedup vs baseline: 1.0544x; 1.0544x over previous
//
#include <hip/hip_runtime.h>
#include <hip/hip_bf16.h>
#include <stdint.h>

// ---------------------------------------------------------------------------
// CrossViewIPAttnProcessor on MI355X (gfx950)
// B=8, Lq=4096, D=1024, Dc=768, H=16, HD=64, text=77 keys, ip=4 keys
// Pipeline:
//   1) all weights fp32->bf16 (single fused kernel)
//   2) Xn[8][96][768]: rows 0..76 = LN(text), 80..83 = raw ip, rest 0
//   3) kv gemm: K_all[bh][96][64], Vt[bh][64][96] (zero-padded keys)
//   4) Q gemm (A fp32 reg-staged->bf16 via v_cvt_pk, B gload_lds) -> d_out half
//   5) attention (MFMA scores + wave-parallel softmax + MFMA PV) -> attn bf16 in ws
//   6) out gemm (both operands gload_lds) + bias -> d_out fp32
// ---------------------------------------------------------------------------

typedef __attribute__((ext_vector_type(8))) short short8;
typedef __attribute__((ext_vector_type(4))) float f32x4;
typedef __attribute__((ext_vector_type(8))) float float8_t;
typedef __attribute__((ext_vector_type(8))) __bf16 bf16x8;
typedef __attribute__((ext_vector_type(4))) __bf16 bf16x4;

// native cast -> compiler emits v_cvt_pk_bf16_f32 (RNE); do NOT hand-roll (m240)
__device__ __forceinline__ ushort f2b(float f) {
  __bf16 h = (__bf16)f;
  return __builtin_bit_cast(ushort, h);
}

__device__ __forceinline__ short8 pack2(float4 a, float4 b) {
  float8_t v;
  v[0] = a.x; v[1] = a.y; v[2] = a.z; v[3] = a.w;
  v[4] = b.x; v[5] = b.y; v[6] = b.z; v[7] = b.w;
  return __builtin_bit_cast(short8, __builtin_convertvector(v, bf16x8));
}

#define GLD16(gp, lp) \
  __builtin_amdgcn_global_load_lds((const __attribute__((address_space(1))) uint32_t*)(gp), \
                                   (__attribute__((address_space(3))) uint32_t*)(lp), 16, 0, 0)

// --------------------- 1) fused fp32 -> bf16 for 6 weights ------------------
struct CvtArgs {
  const float* src[6];
  ushort* dst[6];
  int n4[6];
};

__global__ __launch_bounds__(256) void k_cvt_all(CvtArgs a) {
  int seg = blockIdx.y;
  int i = blockIdx.x * blockDim.x + threadIdx.x;
  if (i >= a.n4[seg]) return;
  float4 v = reinterpret_cast<const float4*>(a.src[seg])[i];
  float8_t f;
  f[0] = v.x; f[1] = v.y; f[2] = v.z; f[3] = v.w; f[4] = 0; f[5] = 0; f[6] = 0; f[7] = 0;
  bf16x4 h;
  h[0] = (__bf16)v.x; h[1] = (__bf16)v.y; h[2] = (__bf16)v.z; h[3] = (__bf16)v.w;
  reinterpret_cast<ushort4*>(a.dst[seg])[i] = __builtin_bit_cast(ushort4, h);
}

// --------------------------- 2) Xn builder ---------------------------------
// grid (96, 8), 256 thr. tok<77: LN(text); 77..79: 0; 80..83: raw ip; 84..95: 0
__global__ __launch_bounds__(256) void k_build_xn(const float* __restrict__ enc,
                                                  const float* __restrict__ lnw,
                                                  const float* __restrict__ lnb,
                                                  ushort* __restrict__ xn) {
  const int Dc = 768;
  int tok = blockIdx.x, b = blockIdx.y, t = threadIdx.x;
  ushort* out = xn + ((size_t)b * 96 + tok) * Dc;
  bool padrow = (tok >= 84) || (tok >= 77 && tok < 80);
  if (padrow) { out[t] = 0; out[t + 256] = 0; out[t + 512] = 0; return; }
  const float* src = (tok < 77) ? enc + ((size_t)b * 81 + tok) * Dc
                                : enc + ((size_t)b * 81 + 77 + (tok - 80)) * Dc;
  float x0 = src[t], x1 = src[t + 256], x2 = src[t + 512];
  if (tok >= 80) { out[t] = f2b(x0); out[t + 256] = f2b(x1); out[t + 512] = f2b(x2); return; }
  float s = x0 + x1 + x2, q = x0 * x0 + x1 * x1 + x2 * x2;
  for (int m = 32; m; m >>= 1) { s += __shfl_xor(s, m, 64); q += __shfl_xor(q, m, 64); }
  __shared__ float rs[4], rq[4];
  int w = t >> 6;
  if ((t & 63) == 0) { rs[w] = s; rq[w] = q; }
  __syncthreads();
  s = rs[0] + rs[1] + rs[2] + rs[3];
  q = rq[0] + rq[1] + rq[2] + rq[3];
  float mean = s * (1.0f / 768.0f);
  float var = q * (1.0f / 768.0f) - mean * mean;
  float rstd = rsqrtf(var + 1e-5f);
  out[t]       = f2b((x0 - mean) * rstd * lnw[t]       + lnb[t]);
  out[t + 256] = f2b((x1 - mean) * rstd * lnw[t + 256] + lnb[t + 256]);
  out[t + 512] = f2b((x2 - mean) * rstd * lnw[t + 512] + lnb[t + 512]);
}

// --------------------------- 3) K/V projection -----------------------------
// C[96][1024] = Xn[96][768] @ W^T, tokens>=80 use W_ip. grid (4 ntiles, 8 b).
// mode 0: K_all[b][h][tok][dd]; mode 1: Vt[b][h][dd][tok]
__global__ __launch_bounds__(256) void k_kv(const ushort* __restrict__ xn,
                                            const ushort* __restrict__ wb,
                                            const ushort* __restrict__ wipb,
                                            ushort* __restrict__ out, int mode) {
  int n0 = blockIdx.x * 256, b = blockIdx.y;
  int t = threadIdx.x, w = t >> 6, l = t & 63, lo = l & 15, hi = l >> 4;
  __shared__ alignas(16) ushort Xs[96 * 32];
  __shared__ alignas(16) ushort Ws[256 * 32];
  __shared__ alignas(16) ushort Wip[256 * 32];
  f32x4 acc[6][4];
  f32x4 zf = {0.f, 0.f, 0.f, 0.f};
  for (int i = 0; i < 6; i++) for (int j = 0; j < 4; j++) acc[i][j] = zf;
  const ushort* xb = xn + (size_t)b * 96 * 768;
  for (int k0 = 0; k0 < 768; k0 += 32) {
    __syncthreads();
    for (int i = t; i < 96 * 16; i += 256) {
      int row = i >> 4, p = i & 15;
      reinterpret_cast<uint32_t*>(Xs)[i] =
          *reinterpret_cast<const uint32_t*>(xb + row * 768 + k0 + p * 2);
    }
    for (int i = t; i < 256 * 16; i += 256) {
      int row = i >> 4, p = i & 15;
      reinterpret_cast<uint32_t*>(Ws)[i] =
          *reinterpret_cast<const uint32_t*>(wb + (size_t)(n0 + row) * 768 + k0 + p * 2);
      reinterpret_cast<uint32_t*>(Wip)[i] =
          *reinterpret_cast<const uint32_t*>(wipb + (size_t)(n0 + row) * 768 + k0 + p * 2);
    }
    __syncthreads();
    short8 a[6], bb[4], bip[4];
    for (int mi = 0; mi < 6; mi++)
      a[mi] = *reinterpret_cast<const short8*>(Xs + (mi * 16 + lo) * 32 + hi * 8);
    for (int ni = 0; ni < 4; ni++) {
      bb[ni]  = *reinterpret_cast<const short8*>(Ws  + (w * 64 + ni * 16 + lo) * 32 + hi * 8);
      bip[ni] = *reinterpret_cast<const short8*>(Wip + (w * 64 + ni * 16 + lo) * 32 + hi * 8);
    }
    for (int ni = 0; ni < 4; ni++) {
      for (int mi = 0; mi < 5; mi++)
        acc[mi][ni] = __builtin_amdgcn_mfma_f32_16x16x32_bf16(a[mi], bb[ni], acc[mi][ni], 0, 0, 0);
      acc[5][ni] = __builtin_amdgcn_mfma_f32_16x16x32_bf16(a[5], bip[ni], acc[5][ni], 0, 0, 0);
    }
  }
  for (int mi = 0; mi < 6; mi++)
    for (int ni = 0; ni < 4; ni++) {
      int col = n0 + w * 64 + ni * 16 + lo;
      int h = col >> 6, dd = col & 63;
      for (int j = 0; j < 4; j++) {
        int tok = mi * 16 + hi * 4 + j;
        ushort v = f2b(acc[mi][ni][j]);
        if (mode == 0) out[(((size_t)b * 16 + h) * 96 + tok) * 64 + dd] = v;
        else           out[(((size_t)b * 16 + h) * 64 + dd) * 96 + tok] = v;
      }
    }
}

// --------------------------- 4) Q projection GEMM --------------------------
// C[32768][1024] bf16 = A[32768][1024] fp32 @ Bw[1024][1024]^T bf16
// 1-D grid 2048, XCD-chunked swizzle; 128x128 tile, BK=32, 4 waves 2x2.
__global__ __launch_bounds__(256) void k_qgemm(const float* __restrict__ A,
                                               const ushort* __restrict__ Bw,
                                               ushort* __restrict__ C) {
  const int K = 1024;
  int wg = blockIdx.x;
  int nid = (wg & 7) * 256 + (wg >> 3);   // XCD-chunked: each XCD owns 32 m-tiles
  int m0 = (nid >> 3) * 128, n0 = (nid & 7) * 128;
  int t = threadIdx.x, w = t >> 6, l = t & 63, lo = l & 15, hi = l >> 4;
  int wm = w >> 1, wn = w & 1;
  __shared__ alignas(16) ushort As[128 * 32];
  __shared__ alignas(16) ushort Bs[128 * 32];
  f32x4 acc[4][4];
  f32x4 zf = {0.f, 0.f, 0.f, 0.f};
  for (int i = 0; i < 4; i++) for (int j = 0; j < 4; j++) acc[i][j] = zf;
  int ar = t >> 2, ac = (t & 3) * 8;
  const float* ga = A + (size_t)(m0 + ar) * K + ac;
  for (int k0 = 0; k0 < K; k0 += 32) {
    float4 v0 = *reinterpret_cast<const float4*>(ga + k0);
    float4 v1 = *reinterpret_cast<const float4*>(ga + k0 + 4);
    float4 v2 = *reinterpret_cast<const float4*>(ga + (size_t)64 * K + k0);
    float4 v3 = *reinterpret_cast<const float4*>(ga + (size_t)64 * K + k0 + 4);
    __syncthreads();
    *reinterpret_cast<short8*>(As + ar * 32 + ac) = pack2(v0, v1);          // byte t*16: linear
    *reinterpret_cast<short8*>(As + (64 + ar) * 32 + ac) = pack2(v2, v3);
    for (int i = 0; i < 2; i++) {
      int unit = (i * 4 + w) * 64 + l;
      int row = unit >> 2, c8 = (unit & 3) * 8;
      GLD16(Bw + (size_t)(n0 + row) * K + k0 + c8, Bs + (i * 4 + w) * 512);
    }
    __syncthreads();
    short8 af[4], bf_[4];
    for (int mi = 0; mi < 4; mi++)
      af[mi] = *reinterpret_cast<const short8*>(As + (wm * 64 + mi * 16 + lo) * 32 + hi * 8);
    for (int ni = 0; ni < 4; ni++)
      bf_[ni] = *reinterpret_cast<const short8*>(Bs + (wn * 64 + ni * 16 + lo) * 32 + hi * 8);
    for (int mi = 0; mi < 4; mi++)
      for (int ni = 0; ni < 4; ni++)
        acc[mi][ni] = __builtin_amdgcn_mfma_f32_16x16x32_bf16(af[mi], bf_[ni], acc[mi][ni], 0, 0, 0);
  }
  for (int mi = 0; mi < 4; mi++)
    for (int ni = 0; ni < 4; ni++)
      for (int j = 0; j < 4; j++) {
        int r = m0 + wm * 64 + mi * 16 + hi * 4 + j;
        int c = n0 + wn * 64 + ni * 16 + lo;
        C[(size_t)r * 1024 + c] = f2b(acc[mi][ni][j]);
      }
}

// --------------------------- 5) attention ----------------------------------
// grid (32 q-tiles, 128 bh). Per wave: 32 q-rows. Keys merged 0..95:
//   0..76 text (softmax A), 80..83 ip (softmax B), rest zero/masked.
__global__ __launch_bounds__(256) void k_attn(const ushort* __restrict__ Q,
                                              const ushort* __restrict__ Kall,
                                              const ushort* __restrict__ Vt,
                                              ushort* __restrict__ O) {
  int q0 = blockIdx.x * 128, bh = blockIdx.y;
  int b = bh >> 4, h = bh & 15;
  int t = threadIdx.x, w = t >> 6, l = t & 63, lo = l & 15, hi = l >> 4;
  __shared__ alignas(16) ushort P[4][32 * 104];  // per-wave P tile, padded stride
  const ushort* Qb = Q + ((size_t)b * 4096 + q0 + w * 32) * 1024 + h * 64;
  short8 qf[2][2];
  for (int mi = 0; mi < 2; mi++)
    for (int ks = 0; ks < 2; ks++)
      qf[mi][ks] = *reinterpret_cast<const short8*>(Qb + (size_t)(mi * 16 + lo) * 1024 + ks * 32 + hi * 8);
  const ushort* Kb = Kall + (size_t)bh * 96 * 64;
  f32x4 s[2][6];
  f32x4 zf = {0.f, 0.f, 0.f, 0.f};
  for (int i = 0; i < 2; i++) for (int j = 0; j < 6; j++) s[i][j] = zf;
  for (int ni = 0; ni < 6; ni++)
    for (int ks = 0; ks < 2; ks++) {
      short8 kf = *reinterpret_cast<const short8*>(Kb + (ni * 16 + lo) * 64 + ks * 32 + hi * 8);
      for (int mi = 0; mi < 2; mi++)
        s[mi][ni] = __builtin_amdgcn_mfma_f32_16x16x32_bf16(qf[mi][ks], kf, s[mi][ni], 0, 0, 0);
    }
  const float SC = 0.125f * 1.44269504088896340736f;  // 1/sqrt(64) * log2(e)
  for (int mi = 0; mi < 2; mi++)
    for (int j = 0; j < 4; j++) {
      float pb[5];
      float mb = -1e30f;
      for (int ni = 0; ni < 5; ni++) {
        int c = ni * 16 + lo;
        float v = s[mi][ni][j] * SC;
        pb[ni] = v;
        if (c < 77) mb = fmaxf(mb, v);
      }
      mb = fmaxf(mb, __shfl_xor(mb, 1, 64));
      mb = fmaxf(mb, __shfl_xor(mb, 2, 64));
      mb = fmaxf(mb, __shfl_xor(mb, 4, 64));
      mb = fmaxf(mb, __shfl_xor(mb, 8, 64));
      float sb = 0.f;
      for (int ni = 0; ni < 5; ni++) {
        int c = ni * 16 + lo;
        float p = (c < 77) ? exp2f(pb[ni] - mb) : 0.f;
        pb[ni] = p; sb += p;
      }
      sb += __shfl_xor(sb, 1, 64); sb += __shfl_xor(sb, 2, 64);
      sb += __shfl_xor(sb, 4, 64); sb += __shfl_xor(sb, 8, 64);
      float rb = 1.0f / sb;
      // ip softmax (cols 80..83 -> ni=5 lanes lo<4)
      float vip = s[mi][5][j] * SC;
      bool val = lo < 4;
      float mip = val ? vip : -1e30f;
      mip = fmaxf(mip, __shfl_xor(mip, 1, 64));
      mip = fmaxf(mip, __shfl_xor(mip, 2, 64));
      mip = fmaxf(mip, __shfl_xor(mip, 4, 64));
      mip = fmaxf(mip, __shfl_xor(mip, 8, 64));
      float pi = val ? exp2f(vip - mip) : 0.f;
      float si = pi;
      si += __shfl_xor(si, 1, 64); si += __shfl_xor(si, 2, 64);
      si += __shfl_xor(si, 4, 64); si += __shfl_xor(si, 8, 64);
      float ri = 1.0f / si;
      int row = mi * 16 + hi * 4 + j;
      ushort* pr = &P[w][row * 104];
      for (int ni = 0; ni < 5; ni++) pr[ni * 16 + lo] = f2b(pb[ni] * rb);
      pr[80 + lo] = f2b(pi * ri);  // zero for lo>=4
    }
  __syncthreads();
  f32x4 o[2][4];
  for (int i = 0; i < 2; i++) for (int j = 0; j < 4; j++) o[i][j] = zf;
  const ushort* Vb = Vt + (size_t)bh * 64 * 96;
  for (int kk = 0; kk < 3; kk++) {
    short8 pf[2];
    for (int mi = 0; mi < 2; mi++)
      pf[mi] = *reinterpret_cast<const short8*>(&P[w][(mi * 16 + lo) * 104 + kk * 32 + hi * 8]);
    for (int dn = 0; dn < 4; dn++) {
      short8 vf = *reinterpret_cast<const short8*>(Vb + (dn * 16 + lo) * 96 + kk * 32 + hi * 8);
      for (int mi = 0; mi < 2; mi++)
        o[mi][dn] = __builtin_amdgcn_mfma_f32_16x16x32_bf16(pf[mi], vf, o[mi][dn], 0, 0, 0);
    }
  }
  ushort* Ob = O + ((size_t)b * 4096 + q0 + w * 32) * 1024 + h * 64;
  for (int mi = 0; mi < 2; mi++)
    for (int dn = 0; dn < 4; dn++)
      for (int j = 0; j < 4; j++)
        Ob[(size_t)(mi * 16 + hi * 4 + j) * 1024 + dn * 16 + lo] = f2b(o[mi][dn][j]);
}

// --------------------------- 6) output GEMM + bias -------------------------
__global__ __launch_bounds__(256) void k_ogemm(const ushort* __restrict__ A,
                                               const ushort* __restrict__ Bw,
                                               const float* __restrict__ bias,
                                               float* __restrict__ C) {
  const int K = 1024;
  int wg = blockIdx.x;
  int nid = (wg & 7) * 256 + (wg >> 3);
  int m0 = (nid >> 3) * 128, n0 = (nid & 7) * 128;
  int t = threadIdx.x, w = t >> 6, l = t & 63, lo = l & 15, hi = l >> 4;
  int wm = w >> 1, wn = w & 1;
  __shared__ alignas(16) ushort As[128 * 32];
  __shared__ alignas(16) ushort Bs[128 * 32];
  f32x4 acc[4][4];
  f32x4 zf = {0.f, 0.f, 0.f, 0.f};
  for (int i = 0; i < 4; i++) for (int j = 0; j < 4; j++) acc[i][j] = zf;
  for (int k0 = 0; k0 < K; k0 += 32) {
    __syncthreads();
    for (int i = 0; i < 2; i++) {
      int unit = (i * 4 + w) * 64 + l;
      int row = unit >> 2, c8 = (unit & 3) * 8;
      GLD16(A  + (size_t)(m0 + row) * K + k0 + c8, As + (i * 4 + w) * 512);
      GLD16(Bw + (size_t)(n0 + row) * K + k0 + c8, Bs + (i * 4 + w) * 512);
    }
    __syncthreads();
    short8 af[4], bf_[4];
    for (int mi = 0; mi < 4; mi++)
      af[mi] = *reinterpret_cast<const short8*>(As + (wm * 64 + mi * 16 + lo) * 32 + hi * 8);
    for (int ni = 0; ni < 4; ni++)
      bf_[ni] = *reinterpret_cast<const short8*>(Bs + (wn * 64 + ni * 16 + lo) * 32 + hi * 8);
    for (int mi = 0; mi < 4; mi++)
      for (int ni = 0; ni < 4; ni++)
        acc[mi][ni] = __builtin_amdgcn_mfma_f32_16x16x32_bf16(af[mi], bf_[ni], acc[mi][ni], 0, 0, 0);
  }
  for (int mi = 0; mi < 4; mi++)
    for (int ni = 0; ni < 4; ni++) {
      int c = n0 + wn * 64 + ni * 16 + lo;
      float bv = bias[c];
      for (int j = 0; j < 4; j++) {
        int r = m0 + wm * 64 + mi * 16 + hi * 4 + j;
        C[(size_t)r * 1024 + c] = acc[mi][ni][j] + bv;
      }
    }
}

// ---------------------------------------------------------------------------
extern "C" void kernel_launch(void* const* d_in, const int* in_sizes, int n_in,
                              void* d_out, int out_size, void* d_ws, size_t ws_size,
                              hipStream_t stream) {
  const float* hs   = (const float*)d_in[0];
  const float* enc  = (const float*)d_in[1];
  const float* Wq   = (const float*)d_in[2];
  const float* Wk   = (const float*)d_in[3];
  const float* Wv   = (const float*)d_in[4];
  const float* Wkip = (const float*)d_in[5];
  const float* Wvip = (const float*)d_in[6];
  const float* Wo   = (const float*)d_in[7];
  const float* bo   = (const float*)d_in[8];
  const float* lnw  = (const float*)d_in[9];
  const float* lnb  = (const float*)d_in[10];
  float* out = (float*)d_out;
  ushort* Qbuf = (ushort*)d_out;  // bf16 Q parked in first 64MB of the 128MB output

  ushort* p = (ushort*)d_ws;      // total ws use: ~82 MB
  ushort* attn    = p; p += (size_t)32768 * 1024;
  ushort* wq_bf   = p; p += (size_t)1024 * 1024;
  ushort* wo_bf   = p; p += (size_t)1024 * 1024;
  ushort* wk_bf   = p; p += (size_t)1024 * 768;
  ushort* wkip_bf = p; p += (size_t)1024 * 768;
  ushort* wv_bf   = p; p += (size_t)1024 * 768;
  ushort* wvip_bf = p; p += (size_t)1024 * 768;
  ushort* xn      = p; p += (size_t)8 * 96 * 768;
  ushort* kall    = p; p += (size_t)8 * 16 * 96 * 64;
  ushort* vtall   = p; p += (size_t)8 * 16 * 96 * 64;

  CvtArgs ca;
  ca.src[0] = Wq;   ca.dst[0] = wq_bf;   ca.n4[0] = 262144;
  ca.src[1] = Wo;   ca.dst[1] = wo_bf;   ca.n4[1] = 262144;
  ca.src[2] = Wk;   ca.dst[2] = wk_bf;   ca.n4[2] = 196608;
  ca.src[3] = Wkip; ca.dst[3] = wkip_bf; ca.n4[3] = 196608;
  ca.src[4] = Wv;   ca.dst[4] = wv_bf;   ca.n4[4] = 196608;
  ca.src[5] = Wvip; ca.dst[5] = wvip_bf; ca.n4[5] = 196608;
  k_cvt_all<<<dim3(1024, 6), 256, 0, stream>>>(ca);
  k_build_xn<<<dim3(96, 8), 256, 0, stream>>>(enc, lnw, lnb, xn);
  k_kv<<<dim3(4, 8), 256, 0, stream>>>(xn, wk_bf, wkip_bf, kall, 0);
  k_kv<<<dim3(4, 8), 256, 0, stream>>>(xn, wv_bf, wvip_bf, vtall, 1);
  k_qgemm<<<2048, 256, 0, stream>>>(hs, wq_bf, Qbuf);
  k_attn<<<dim3(32, 128), 256, 0, stream>>>(Qbuf, kall, vtall, attn);
  k_ogemm<<<2048, 256, 0, stream>>>(attn, wo_bf, bo, out);
}

// Round 3
// 436.101 us; speedup vs baseline: 1.0809x; 1.0252x over previous
//
#include <hip/hip_runtime.h>
#include <hip/hip_bf16.h>
#include <stdint.h>

// ---------------------------------------------------------------------------
// CrossViewIPAttnProcessor on MI355X (gfx950)
// B=8, Lq=4096, D=1024, Dc=768, H=16, HD=64, text=77 keys, ip=4 keys
// Round 3: both big GEMMs -> 256x256 tile, BK=64, 8-wave, double-buffered
// pipeline with counted vmcnt (T3+T4) + setprio (T5). Linear LDS (T2 next).
// ---------------------------------------------------------------------------

typedef __attribute__((ext_vector_type(8))) short short8;
typedef __attribute__((ext_vector_type(4))) float f32x4;
typedef __attribute__((ext_vector_type(8))) float float8_t;
typedef __attribute__((ext_vector_type(8))) __bf16 bf16x8;
typedef __attribute__((ext_vector_type(4))) __bf16 bf16x4;

__device__ __forceinline__ ushort f2b(float f) {
  __bf16 h = (__bf16)f;
  return __builtin_bit_cast(ushort, h);
}

__device__ __forceinline__ short8 pack2(float4 a, float4 b) {
  float8_t v;
  v[0] = a.x; v[1] = a.y; v[2] = a.z; v[3] = a.w;
  v[4] = b.x; v[5] = b.y; v[6] = b.z; v[7] = b.w;
  return __builtin_bit_cast(short8, __builtin_convertvector(v, bf16x8));
}

#define GLD16(gp, lp) \
  __builtin_amdgcn_global_load_lds((const __attribute__((address_space(1))) uint32_t*)(gp), \
                                   (__attribute__((address_space(3))) uint32_t*)(lp), 16, 0, 0)

#define FENCE_SCHED() __builtin_amdgcn_sched_barrier(0)

// --------------------- 1) fused fp32 -> bf16 for 6 weights ------------------
struct CvtArgs {
  const float* src[6];
  ushort* dst[6];
  int n4[6];
};

__global__ __launch_bounds__(256) void k_cvt_all(CvtArgs a) {
  int seg = blockIdx.y;
  int i = blockIdx.x * blockDim.x + threadIdx.x;
  if (i >= a.n4[seg]) return;
  float4 v = reinterpret_cast<const float4*>(a.src[seg])[i];
  bf16x4 h;
  h[0] = (__bf16)v.x; h[1] = (__bf16)v.y; h[2] = (__bf16)v.z; h[3] = (__bf16)v.w;
  reinterpret_cast<ushort4*>(a.dst[seg])[i] = __builtin_bit_cast(ushort4, h);
}

// --------------------------- 2) Xn builder ---------------------------------
__global__ __launch_bounds__(256) void k_build_xn(const float* __restrict__ enc,
                                                  const float* __restrict__ lnw,
                                                  const float* __restrict__ lnb,
                                                  ushort* __restrict__ xn) {
  const int Dc = 768;
  int tok = blockIdx.x, b = blockIdx.y, t = threadIdx.x;
  ushort* out = xn + ((size_t)b * 96 + tok) * Dc;
  bool padrow = (tok >= 84) || (tok >= 77 && tok < 80);
  if (padrow) { out[t] = 0; out[t + 256] = 0; out[t + 512] = 0; return; }
  const float* src = (tok < 77) ? enc + ((size_t)b * 81 + tok) * Dc
                                : enc + ((size_t)b * 81 + 77 + (tok - 80)) * Dc;
  float x0 = src[t], x1 = src[t + 256], x2 = src[t + 512];
  if (tok >= 80) { out[t] = f2b(x0); out[t + 256] = f2b(x1); out[t + 512] = f2b(x2); return; }
  float s = x0 + x1 + x2, q = x0 * x0 + x1 * x1 + x2 * x2;
  for (int m = 32; m; m >>= 1) { s += __shfl_xor(s, m, 64); q += __shfl_xor(q, m, 64); }
  __shared__ float rs[4], rq[4];
  int w = t >> 6;
  if ((t & 63) == 0) { rs[w] = s; rq[w] = q; }
  __syncthreads();
  s = rs[0] + rs[1] + rs[2] + rs[3];
  q = rq[0] + rq[1] + rq[2] + rq[3];
  float mean = s * (1.0f / 768.0f);
  float var = q * (1.0f / 768.0f) - mean * mean;
  float rstd = rsqrtf(var + 1e-5f);
  out[t]       = f2b((x0 - mean) * rstd * lnw[t]       + lnb[t]);
  out[t + 256] = f2b((x1 - mean) * rstd * lnw[t + 256] + lnb[t + 256]);
  out[t + 512] = f2b((x2 - mean) * rstd * lnw[t + 512] + lnb[t + 512]);
}

// --------------------------- 3) K/V projection -----------------------------
__global__ __launch_bounds__(256) void k_kv(const ushort* __restrict__ xn,
                                            const ushort* __restrict__ wb,
                                            const ushort* __restrict__ wipb,
                                            ushort* __restrict__ out, int mode) {
  int n0 = blockIdx.x * 256, b = blockIdx.y;
  int t = threadIdx.x, w = t >> 6, l = t & 63, lo = l & 15, hi = l >> 4;
  __shared__ alignas(16) ushort Xs[96 * 32];
  __shared__ alignas(16) ushort Ws[256 * 32];
  __shared__ alignas(16) ushort Wip[256 * 32];
  f32x4 acc[6][4];
  f32x4 zf = {0.f, 0.f, 0.f, 0.f};
  for (int i = 0; i < 6; i++) for (int j = 0; j < 4; j++) acc[i][j] = zf;
  const ushort* xb = xn + (size_t)b * 96 * 768;
  for (int k0 = 0; k0 < 768; k0 += 32) {
    __syncthreads();
    for (int i = t; i < 96 * 16; i += 256) {
      int row = i >> 4, p = i & 15;
      reinterpret_cast<uint32_t*>(Xs)[i] =
          *reinterpret_cast<const uint32_t*>(xb + row * 768 + k0 + p * 2);
    }
    for (int i = t; i < 256 * 16; i += 256) {
      int row = i >> 4, p = i & 15;
      reinterpret_cast<uint32_t*>(Ws)[i] =
          *reinterpret_cast<const uint32_t*>(wb + (size_t)(n0 + row) * 768 + k0 + p * 2);
      reinterpret_cast<uint32_t*>(Wip)[i] =
          *reinterpret_cast<const uint32_t*>(wipb + (size_t)(n0 + row) * 768 + k0 + p * 2);
    }
    __syncthreads();
    short8 a[6], bb[4], bip[4];
    for (int mi = 0; mi < 6; mi++)
      a[mi] = *reinterpret_cast<const short8*>(Xs + (mi * 16 + lo) * 32 + hi * 8);
    for (int ni = 0; ni < 4; ni++) {
      bb[ni]  = *reinterpret_cast<const short8*>(Ws  + (w * 64 + ni * 16 + lo) * 32 + hi * 8);
      bip[ni] = *reinterpret_cast<const short8*>(Wip + (w * 64 + ni * 16 + lo) * 32 + hi * 8);
    }
    for (int ni = 0; ni < 4; ni++) {
      for (int mi = 0; mi < 5; mi++)
        acc[mi][ni] = __builtin_amdgcn_mfma_f32_16x16x32_bf16(a[mi], bb[ni], acc[mi][ni], 0, 0, 0);
      acc[5][ni] = __builtin_amdgcn_mfma_f32_16x16x32_bf16(a[5], bip[ni], acc[5][ni], 0, 0, 0);
    }
  }
  for (int mi = 0; mi < 6; mi++)
    for (int ni = 0; ni < 4; ni++) {
      int col = n0 + w * 64 + ni * 16 + lo;
      int h = col >> 6, dd = col & 63;
      for (int j = 0; j < 4; j++) {
        int tok = mi * 16 + hi * 4 + j;
        ushort v = f2b(acc[mi][ni][j]);
        if (mode == 0) out[(((size_t)b * 16 + h) * 96 + tok) * 64 + dd] = v;
        else           out[(((size_t)b * 16 + h) * 64 + dd) * 96 + tok] = v;
      }
    }
}

// --------------------------- 4) Q projection GEMM --------------------------
// C[32768][1024] bf16 = A[32768][1024] fp32 @ Bw[1024][1024]^T bf16
// 256x256 tile, BK=64, 8 waves (2x4), dbuf + counted vmcnt pipeline.
// A: reg-staged fp32->bf16 (issue-early / ds_write-late); B: global_load_lds.
__global__ __launch_bounds__(512, 2) void k_qgemm(const float* __restrict__ A,
                                                  const ushort* __restrict__ Bw,
                                                  ushort* __restrict__ C) {
  const int K = 1024, NT = 16;
  int wg = blockIdx.x;
  int nid = (wg & 7) * 64 + (wg >> 3);      // XCD-chunked, nwg=512 (%8==0)
  int m0 = (nid >> 2) * 256, n0 = (nid & 3) * 256;
  int t = threadIdx.x, wid = t >> 6, l = t & 63, lo = l & 15, hi = l >> 4;
  int wr = wid >> 2, wc = wid & 3;
  __shared__ alignas(16) ushort AS[2][256 * 64];
  __shared__ alignas(16) ushort BS[2][256 * 64];
  f32x4 acc[8][4];
  f32x4 zf = {0.f, 0.f, 0.f, 0.f};
#pragma unroll
  for (int i = 0; i < 8; i++)
#pragma unroll
    for (int j = 0; j < 4; j++) acc[i][j] = zf;
  int tr = t >> 3, tc = t & 7;
  const float*  gA = A  + (size_t)(m0 + tr) * K + tc * 8;
  const ushort* gB = Bw + (size_t)(n0 + tr) * K + tc * 8;
  float4 av[4][2];
  // ---- prologue: stage tile 0 ----
#pragma unroll
  for (int s = 0; s < 4; s++) {
    av[s][0] = *reinterpret_cast<const float4*>(gA + (size_t)s * 64 * K);
    av[s][1] = *reinterpret_cast<const float4*>(gA + (size_t)s * 64 * K + 4);
  }
#pragma unroll
  for (int s = 0; s < 4; s++)
    GLD16(gB + (size_t)s * 64 * K, &BS[0][s * 4096 + wid * 512]);
#pragma unroll
  for (int s = 0; s < 4; s++)
    *reinterpret_cast<short8*>(&AS[0][(s * 64 + tr) * 64 + tc * 8]) = pack2(av[s][0], av[s][1]);
  asm volatile("s_waitcnt lgkmcnt(0)" ::: "memory");
  __builtin_amdgcn_s_barrier();
  FENCE_SCHED();
  int cur = 0;
  for (int kt = 0; kt < NT; kt++) {
    // (a) issue next tile's loads: 8 reg A-loads + 4 B gload_lds per wave
    if (kt + 1 < NT) {
      const float*  gAk = gA + (kt + 1) * 64;
      const ushort* gBk = gB + (kt + 1) * 64;
#pragma unroll
      for (int s = 0; s < 4; s++) {
        av[s][0] = *reinterpret_cast<const float4*>(gAk + (size_t)s * 64 * K);
        av[s][1] = *reinterpret_cast<const float4*>(gAk + (size_t)s * 64 * K + 4);
      }
#pragma unroll
      for (int s = 0; s < 4; s++)
        GLD16(gBk + (size_t)s * 64 * K, &BS[cur ^ 1][s * 4096 + wid * 512]);
      // (b) counted wait: retire current tile's 4 B gloads, keep 12 in flight
      asm volatile("s_waitcnt vmcnt(12)" ::: "memory");
    } else {
      asm volatile("s_waitcnt vmcnt(0)" ::: "memory");
    }
    __builtin_amdgcn_s_barrier();
    FENCE_SCHED();
    // (c) 4 phases: 8 ds_read_b128 + 16 MFMA each
    const ushort* pA = &AS[cur][(wr * 128 + lo) * 64 + hi * 8];
    const ushort* pB = &BS[cur][(wc * 64 + lo) * 64 + hi * 8];
#pragma unroll
    for (int kk = 0; kk < 2; kk++)
#pragma unroll
      for (int mh = 0; mh < 2; mh++) {
        short8 af[4], bfr[4];
#pragma unroll
        for (int q = 0; q < 4; q++)
          af[q] = *reinterpret_cast<const short8*>(pA + ((mh * 4 + q) * 16) * 64 + kk * 32);
#pragma unroll
        for (int n = 0; n < 4; n++)
          bfr[n] = *reinterpret_cast<const short8*>(pB + (n * 16) * 64 + kk * 32);
        __builtin_amdgcn_s_setprio(1);
#pragma unroll
        for (int q = 0; q < 4; q++)
#pragma unroll
          for (int n = 0; n < 4; n++)
            acc[mh * 4 + q][n] =
                __builtin_amdgcn_mfma_f32_16x16x32_bf16(af[q], bfr[n], acc[mh * 4 + q][n], 0, 0, 0);
        __builtin_amdgcn_s_setprio(0);
      }
    // (d) write-late: cvt + ds_write next A tile (compiler auto-waits the av loads)
    if (kt + 1 < NT) {
#pragma unroll
      for (int s = 0; s < 4; s++)
        *reinterpret_cast<short8*>(&AS[cur ^ 1][(s * 64 + tr) * 64 + tc * 8]) =
            pack2(av[s][0], av[s][1]);
    }
    // (e) close: all LDS ops drained, then barrier
    asm volatile("s_waitcnt lgkmcnt(0)" ::: "memory");
    __builtin_amdgcn_s_barrier();
    FENCE_SCHED();
    cur ^= 1;
  }
  // epilogue: bf16 C
#pragma unroll
  for (int mi = 0; mi < 8; mi++)
#pragma unroll
    for (int n = 0; n < 4; n++)
#pragma unroll
      for (int j = 0; j < 4; j++) {
        int r = m0 + wr * 128 + mi * 16 + hi * 4 + j;
        int c = n0 + wc * 64 + n * 16 + lo;
        C[(size_t)r * 1024 + c] = f2b(acc[mi][n][j]);
      }
}

// --------------------------- 5) attention ----------------------------------
__global__ __launch_bounds__(256) void k_attn(const ushort* __restrict__ Q,
                                              const ushort* __restrict__ Kall,
                                              const ushort* __restrict__ Vt,
                                              ushort* __restrict__ O) {
  int q0 = blockIdx.x * 128, bh = blockIdx.y;
  int b = bh >> 4, h = bh & 15;
  int t = threadIdx.x, w = t >> 6, l = t & 63, lo = l & 15, hi = l >> 4;
  __shared__ alignas(16) ushort P[4][32 * 104];
  const ushort* Qb = Q + ((size_t)b * 4096 + q0 + w * 32) * 1024 + h * 64;
  short8 qf[2][2];
  for (int mi = 0; mi < 2; mi++)
    for (int ks = 0; ks < 2; ks++)
      qf[mi][ks] = *reinterpret_cast<const short8*>(Qb + (size_t)(mi * 16 + lo) * 1024 + ks * 32 + hi * 8);
  const ushort* Kb = Kall + (size_t)bh * 96 * 64;
  f32x4 s[2][6];
  f32x4 zf = {0.f, 0.f, 0.f, 0.f};
  for (int i = 0; i < 2; i++) for (int j = 0; j < 6; j++) s[i][j] = zf;
  for (int ni = 0; ni < 6; ni++)
    for (int ks = 0; ks < 2; ks++) {
      short8 kf = *reinterpret_cast<const short8*>(Kb + (ni * 16 + lo) * 64 + ks * 32 + hi * 8);
      for (int mi = 0; mi < 2; mi++)
        s[mi][ni] = __builtin_amdgcn_mfma_f32_16x16x32_bf16(qf[mi][ks], kf, s[mi][ni], 0, 0, 0);
    }
  const float SC = 0.125f * 1.44269504088896340736f;
  for (int mi = 0; mi < 2; mi++)
    for (int j = 0; j < 4; j++) {
      float pb[5];
      float mb = -1e30f;
      for (int ni = 0; ni < 5; ni++) {
        int c = ni * 16 + lo;
        float v = s[mi][ni][j] * SC;
        pb[ni] = v;
        if (c < 77) mb = fmaxf(mb, v);
      }
      mb = fmaxf(mb, __shfl_xor(mb, 1, 64));
      mb = fmaxf(mb, __shfl_xor(mb, 2, 64));
      mb = fmaxf(mb, __shfl_xor(mb, 4, 64));
      mb = fmaxf(mb, __shfl_xor(mb, 8, 64));
      float sb = 0.f;
      for (int ni = 0; ni < 5; ni++) {
        int c = ni * 16 + lo;
        float p = (c < 77) ? exp2f(pb[ni] - mb) : 0.f;
        pb[ni] = p; sb += p;
      }
      sb += __shfl_xor(sb, 1, 64); sb += __shfl_xor(sb, 2, 64);
      sb += __shfl_xor(sb, 4, 64); sb += __shfl_xor(sb, 8, 64);
      float rb = 1.0f / sb;
      float vip = s[mi][5][j] * SC;
      bool val = lo < 4;
      float mip = val ? vip : -1e30f;
      mip = fmaxf(mip, __shfl_xor(mip, 1, 64));
      mip = fmaxf(mip, __shfl_xor(mip, 2, 64));
      mip = fmaxf(mip, __shfl_xor(mip, 4, 64));
      mip = fmaxf(mip, __shfl_xor(mip, 8, 64));
      float pi = val ? exp2f(vip - mip) : 0.f;
      float si = pi;
      si += __shfl_xor(si, 1, 64); si += __shfl_xor(si, 2, 64);
      si += __shfl_xor(si, 4, 64); si += __shfl_xor(si, 8, 64);
      float ri = 1.0f / si;
      int row = mi * 16 + hi * 4 + j;
      ushort* pr = &P[w][row * 104];
      for (int ni = 0; ni < 5; ni++) pr[ni * 16 + lo] = f2b(pb[ni] * rb);
      pr[80 + lo] = f2b(pi * ri);
    }
  __syncthreads();
  f32x4 o[2][4];
  for (int i = 0; i < 2; i++) for (int j = 0; j < 4; j++) o[i][j] = zf;
  const ushort* Vb = Vt + (size_t)bh * 64 * 96;
  for (int kk = 0; kk < 3; kk++) {
    short8 pf[2];
    for (int mi = 0; mi < 2; mi++)
      pf[mi] = *reinterpret_cast<const short8*>(&P[w][(mi * 16 + lo) * 104 + kk * 32 + hi * 8]);
    for (int dn = 0; dn < 4; dn++) {
      short8 vf = *reinterpret_cast<const short8*>(Vb + (dn * 16 + lo) * 96 + kk * 32 + hi * 8);
      for (int mi = 0; mi < 2; mi++)
        o[mi][dn] = __builtin_amdgcn_mfma_f32_16x16x32_bf16(pf[mi], vf, o[mi][dn], 0, 0, 0);
    }
  }
  ushort* Ob = O + ((size_t)b * 4096 + q0 + w * 32) * 1024 + h * 64;
  for (int mi = 0; mi < 2; mi++)
    for (int dn = 0; dn < 4; dn++)
      for (int j = 0; j < 4; j++)
        Ob[(size_t)(mi * 16 + hi * 4 + j) * 1024 + dn * 16 + lo] = f2b(o[mi][dn][j]);
}

// --------------------------- 6) output GEMM + bias -------------------------
// C[32768][1024] fp32 = attn bf16 @ Wo^T bf16 + bias; same pipeline, both
// operands via global_load_lds (8 gloads/wave per K-tile).
__global__ __launch_bounds__(512, 2) void k_ogemm(const ushort* __restrict__ A,
                                                  const ushort* __restrict__ Bw,
                                                  const float* __restrict__ bias,
                                                  float* __restrict__ C) {
  const int K = 1024, NT = 16;
  int wg = blockIdx.x;
  int nid = (wg & 7) * 64 + (wg >> 3);
  int m0 = (nid >> 2) * 256, n0 = (nid & 3) * 256;
  int t = threadIdx.x, wid = t >> 6, l = t & 63, lo = l & 15, hi = l >> 4;
  int wr = wid >> 2, wc = wid & 3;
  __shared__ alignas(16) ushort AS[2][256 * 64];
  __shared__ alignas(16) ushort BS[2][256 * 64];
  f32x4 acc[8][4];
  f32x4 zf = {0.f, 0.f, 0.f, 0.f};
#pragma unroll
  for (int i = 0; i < 8; i++)
#pragma unroll
    for (int j = 0; j < 4; j++) acc[i][j] = zf;
  int tr = t >> 3, tc = t & 7;
  const ushort* gA = A  + (size_t)(m0 + tr) * K + tc * 8;
  const ushort* gB = Bw + (size_t)(n0 + tr) * K + tc * 8;
  // prologue: stage tile 0
#pragma unroll
  for (int s = 0; s < 4; s++)
    GLD16(gA + (size_t)s * 64 * K, &AS[0][s * 4096 + wid * 512]);
#pragma unroll
  for (int s = 0; s < 4; s++)
    GLD16(gB + (size_t)s * 64 * K, &BS[0][s * 4096 + wid * 512]);
  int cur = 0;
  for (int kt = 0; kt < NT; kt++) {
    if (kt + 1 < NT) {
      const ushort* gAk = gA + (kt + 1) * 64;
      const ushort* gBk = gB + (kt + 1) * 64;
#pragma unroll
      for (int s = 0; s < 4; s++)
        GLD16(gAk + (size_t)s * 64 * K, &AS[cur ^ 1][s * 4096 + wid * 512]);
#pragma unroll
      for (int s = 0; s < 4; s++)
        GLD16(gBk + (size_t)s * 64 * K, &BS[cur ^ 1][s * 4096 + wid * 512]);
      asm volatile("s_waitcnt vmcnt(8)" ::: "memory");
    } else {
      asm volatile("s_waitcnt vmcnt(0)" ::: "memory");
    }
    __builtin_amdgcn_s_barrier();
    FENCE_SCHED();
    const ushort* pA = &AS[cur][(wr * 128 + lo) * 64 + hi * 8];
    const ushort* pB = &BS[cur][(wc * 64 + lo) * 64 + hi * 8];
#pragma unroll
    for (int kk = 0; kk < 2; kk++)
#pragma unroll
      for (int mh = 0; mh < 2; mh++) {
        short8 af[4], bfr[4];
#pragma unroll
        for (int q = 0; q < 4; q++)
          af[q] = *reinterpret_cast<const short8*>(pA + ((mh * 4 + q) * 16) * 64 + kk * 32);
#pragma unroll
        for (int n = 0; n < 4; n++)
          bfr[n] = *reinterpret_cast<const short8*>(pB + (n * 16) * 64 + kk * 32);
        __builtin_amdgcn_s_setprio(1);
#pragma unroll
        for (int q = 0; q < 4; q++)
#pragma unroll
          for (int n = 0; n < 4; n++)
            acc[mh * 4 + q][n] =
                __builtin_amdgcn_mfma_f32_16x16x32_bf16(af[q], bfr[n], acc[mh * 4 + q][n], 0, 0, 0);
        __builtin_amdgcn_s_setprio(0);
      }
    asm volatile("s_waitcnt lgkmcnt(0)" ::: "memory");
    __builtin_amdgcn_s_barrier();
    FENCE_SCHED();
    cur ^= 1;
  }
#pragma unroll
  for (int n = 0; n < 4; n++) {
    int c = n0 + wc * 64 + n * 16 + lo;
    float bv = bias[c];
#pragma unroll
    for (int mi = 0; mi < 8; mi++)
#pragma unroll
      for (int j = 0; j < 4; j++) {
        int r = m0 + wr * 128 + mi * 16 + hi * 4 + j;
        C[(size_t)r * 1024 + c] = acc[mi][n][j] + bv;
      }
  }
}

// ---------------------------------------------------------------------------
extern "C" void kernel_launch(void* const* d_in, const int* in_sizes, int n_in,
                              void* d_out, int out_size, void* d_ws, size_t ws_size,
                              hipStream_t stream) {
  const float* hs   = (const float*)d_in[0];
  const float* enc  = (const float*)d_in[1];
  const float* Wq   = (const float*)d_in[2];
  const float* Wk   = (const float*)d_in[3];
  const float* Wv   = (const float*)d_in[4];
  const float* Wkip = (const float*)d_in[5];
  const float* Wvip = (const float*)d_in[6];
  const float* Wo   = (const float*)d_in[7];
  const float* bo   = (const float*)d_in[8];
  const float* lnw  = (const float*)d_in[9];
  const float* lnb  = (const float*)d_in[10];
  float* out = (float*)d_out;
  ushort* Qbuf = (ushort*)d_out;  // bf16 Q parked in first 64MB of the 128MB output

  ushort* p = (ushort*)d_ws;
  ushort* attn    = p; p += (size_t)32768 * 1024;
  ushort* wq_bf   = p; p += (size_t)1024 * 1024;
  ushort* wo_bf   = p; p += (size_t)1024 * 1024;
  ushort* wk_bf   = p; p += (size_t)1024 * 768;
  ushort* wkip_bf = p; p += (size_t)1024 * 768;
  ushort* wv_bf   = p; p += (size_t)1024 * 768;
  ushort* wvip_bf = p; p += (size_t)1024 * 768;
  ushort* xn      = p; p += (size_t)8 * 96 * 768;
  ushort* kall    = p; p += (size_t)8 * 16 * 96 * 64;
  ushort* vtall   = p; p += (size_t)8 * 16 * 96 * 64;

  CvtArgs ca;
  ca.src[0] = Wq;   ca.dst[0] = wq_bf;   ca.n4[0] = 262144;
  ca.src[1] = Wo;   ca.dst[1] = wo_bf;   ca.n4[1] = 262144;
  ca.src[2] = Wk;   ca.dst[2] = wk_bf;   ca.n4[2] = 196608;
  ca.src[3] = Wkip; ca.dst[3] = wkip_bf; ca.n4[3] = 196608;
  ca.src[4] = Wv;   ca.dst[4] = wv_bf;   ca.n4[4] = 196608;
  ca.src[5] = Wvip; ca.dst[5] = wvip_bf; ca.n4[5] = 196608;
  k_cvt_all<<<dim3(1024, 6), 256, 0, stream>>>(ca);
  k_build_xn<<<dim3(96, 8), 256, 0, stream>>>(enc, lnw, lnb, xn);
  k_kv<<<dim3(4, 8), 256, 0, stream>>>(xn, wk_bf, wkip_bf, kall, 0);
  k_kv<<<dim3(4, 8), 256, 0, stream>>>(xn, wv_bf, wvip_bf, vtall, 1);
  k_qgemm<<<512, 512, 0, stream>>>(hs, wq_bf, Qbuf);
  k_attn<<<dim3(32, 128), 256, 0, stream>>>(Qbuf, kall, vtall, attn);
  k_ogemm<<<512, 512, 0, stream>>>(attn, wo_bf, bo, out);
}

// Round 4
// 415.593 us; speedup vs baseline: 1.1343x; 1.0493x over previous
//
#include <hip/hip_runtime.h>
#include <hip/hip_bf16.h>
#include <stdint.h>

// ---------------------------------------------------------------------------
// CrossViewIPAttnProcessor on MI355X (gfx950)
// B=8, Lq=4096, D=1024, Dc=768, H=16, HD=64, text=77 keys, ip=4 keys
// Round 4: + T2 XOR-swizzle on both GEMM LDS tiles (chunk ^= row&7).
//   writes linear (gload_lds-compatible), global source col pre-swizzled,
//   reads XOR'd. Pipeline (T3+T4+T5) unchanged from round 3.
// ---------------------------------------------------------------------------

typedef __attribute__((ext_vector_type(8))) short short8;
typedef __attribute__((ext_vector_type(4))) float f32x4;
typedef __attribute__((ext_vector_type(8))) float float8_t;
typedef __attribute__((ext_vector_type(8))) __bf16 bf16x8;
typedef __attribute__((ext_vector_type(4))) __bf16 bf16x4;

__device__ __forceinline__ ushort f2b(float f) {
  __bf16 h = (__bf16)f;
  return __builtin_bit_cast(ushort, h);
}

__device__ __forceinline__ short8 pack2(float4 a, float4 b) {
  float8_t v;
  v[0] = a.x; v[1] = a.y; v[2] = a.z; v[3] = a.w;
  v[4] = b.x; v[5] = b.y; v[6] = b.z; v[7] = b.w;
  return __builtin_bit_cast(short8, __builtin_convertvector(v, bf16x8));
}

#define GLD16(gp, lp) \
  __builtin_amdgcn_global_load_lds((const __attribute__((address_space(1))) uint32_t*)(gp), \
                                   (__attribute__((address_space(3))) uint32_t*)(lp), 16, 0, 0)

#define FENCE_SCHED() __builtin_amdgcn_sched_barrier(0)

// --------------------- 1) fused fp32 -> bf16 for 6 weights ------------------
struct CvtArgs {
  const float* src[6];
  ushort* dst[6];
  int n4[6];
};

__global__ __launch_bounds__(256) void k_cvt_all(CvtArgs a) {
  int seg = blockIdx.y;
  int i = blockIdx.x * blockDim.x + threadIdx.x;
  if (i >= a.n4[seg]) return;
  float4 v = reinterpret_cast<const float4*>(a.src[seg])[i];
  bf16x4 h;
  h[0] = (__bf16)v.x; h[1] = (__bf16)v.y; h[2] = (__bf16)v.z; h[3] = (__bf16)v.w;
  reinterpret_cast<ushort4*>(a.dst[seg])[i] = __builtin_bit_cast(ushort4, h);
}

// --------------------------- 2) Xn builder ---------------------------------
__global__ __launch_bounds__(256) void k_build_xn(const float* __restrict__ enc,
                                                  const float* __restrict__ lnw,
                                                  const float* __restrict__ lnb,
                                                  ushort* __restrict__ xn) {
  const int Dc = 768;
  int tok = blockIdx.x, b = blockIdx.y, t = threadIdx.x;
  ushort* out = xn + ((size_t)b * 96 + tok) * Dc;
  bool padrow = (tok >= 84) || (tok >= 77 && tok < 80);
  if (padrow) { out[t] = 0; out[t + 256] = 0; out[t + 512] = 0; return; }
  const float* src = (tok < 77) ? enc + ((size_t)b * 81 + tok) * Dc
                                : enc + ((size_t)b * 81 + 77 + (tok - 80)) * Dc;
  float x0 = src[t], x1 = src[t + 256], x2 = src[t + 512];
  if (tok >= 80) { out[t] = f2b(x0); out[t + 256] = f2b(x1); out[t + 512] = f2b(x2); return; }
  float s = x0 + x1 + x2, q = x0 * x0 + x1 * x1 + x2 * x2;
  for (int m = 32; m; m >>= 1) { s += __shfl_xor(s, m, 64); q += __shfl_xor(q, m, 64); }
  __shared__ float rs[4], rq[4];
  int w = t >> 6;
  if ((t & 63) == 0) { rs[w] = s; rq[w] = q; }
  __syncthreads();
  s = rs[0] + rs[1] + rs[2] + rs[3];
  q = rq[0] + rq[1] + rq[2] + rq[3];
  float mean = s * (1.0f / 768.0f);
  float var = q * (1.0f / 768.0f) - mean * mean;
  float rstd = rsqrtf(var + 1e-5f);
  out[t]       = f2b((x0 - mean) * rstd * lnw[t]       + lnb[t]);
  out[t + 256] = f2b((x1 - mean) * rstd * lnw[t + 256] + lnb[t + 256]);
  out[t + 512] = f2b((x2 - mean) * rstd * lnw[t + 512] + lnb[t + 512]);
}

// --------------------------- 3) K/V projection -----------------------------
__global__ __launch_bounds__(256) void k_kv(const ushort* __restrict__ xn,
                                            const ushort* __restrict__ wb,
                                            const ushort* __restrict__ wipb,
                                            ushort* __restrict__ out, int mode) {
  int n0 = blockIdx.x * 256, b = blockIdx.y;
  int t = threadIdx.x, w = t >> 6, l = t & 63, lo = l & 15, hi = l >> 4;
  __shared__ alignas(16) ushort Xs[96 * 32];
  __shared__ alignas(16) ushort Ws[256 * 32];
  __shared__ alignas(16) ushort Wip[256 * 32];
  f32x4 acc[6][4];
  f32x4 zf = {0.f, 0.f, 0.f, 0.f};
  for (int i = 0; i < 6; i++) for (int j = 0; j < 4; j++) acc[i][j] = zf;
  const ushort* xb = xn + (size_t)b * 96 * 768;
  for (int k0 = 0; k0 < 768; k0 += 32) {
    __syncthreads();
    for (int i = t; i < 96 * 16; i += 256) {
      int row = i >> 4, p = i & 15;
      reinterpret_cast<uint32_t*>(Xs)[i] =
          *reinterpret_cast<const uint32_t*>(xb + row * 768 + k0 + p * 2);
    }
    for (int i = t; i < 256 * 16; i += 256) {
      int row = i >> 4, p = i & 15;
      reinterpret_cast<uint32_t*>(Ws)[i] =
          *reinterpret_cast<const uint32_t*>(wb + (size_t)(n0 + row) * 768 + k0 + p * 2);
      reinterpret_cast<uint32_t*>(Wip)[i] =
          *reinterpret_cast<const uint32_t*>(wipb + (size_t)(n0 + row) * 768 + k0 + p * 2);
    }
    __syncthreads();
    short8 a[6], bb[4], bip[4];
    for (int mi = 0; mi < 6; mi++)
      a[mi] = *reinterpret_cast<const short8*>(Xs + (mi * 16 + lo) * 32 + hi * 8);
    for (int ni = 0; ni < 4; ni++) {
      bb[ni]  = *reinterpret_cast<const short8*>(Ws  + (w * 64 + ni * 16 + lo) * 32 + hi * 8);
      bip[ni] = *reinterpret_cast<const short8*>(Wip + (w * 64 + ni * 16 + lo) * 32 + hi * 8);
    }
    for (int ni = 0; ni < 4; ni++) {
      for (int mi = 0; mi < 5; mi++)
        acc[mi][ni] = __builtin_amdgcn_mfma_f32_16x16x32_bf16(a[mi], bb[ni], acc[mi][ni], 0, 0, 0);
      acc[5][ni] = __builtin_amdgcn_mfma_f32_16x16x32_bf16(a[5], bip[ni], acc[5][ni], 0, 0, 0);
    }
  }
  for (int mi = 0; mi < 6; mi++)
    for (int ni = 0; ni < 4; ni++) {
      int col = n0 + w * 64 + ni * 16 + lo;
      int h = col >> 6, dd = col & 63;
      for (int j = 0; j < 4; j++) {
        int tok = mi * 16 + hi * 4 + j;
        ushort v = f2b(acc[mi][ni][j]);
        if (mode == 0) out[(((size_t)b * 16 + h) * 96 + tok) * 64 + dd] = v;
        else           out[(((size_t)b * 16 + h) * 64 + dd) * 96 + tok] = v;
      }
    }
}

// --------------------------- 4) Q projection GEMM --------------------------
// C[32768][1024] bf16 = A[32768][1024] fp32 @ Bw[1024][1024]^T bf16
// 256x256 tile, BK=64, 8 waves (2x4), dbuf + counted vmcnt pipeline.
// T2: LDS physical chunk = logical chunk ^ (row&7); writes linear, global
// source col pre-swizzled, reads XOR'd.
__global__ __launch_bounds__(512, 2) void k_qgemm(const float* __restrict__ A,
                                                  const ushort* __restrict__ Bw,
                                                  ushort* __restrict__ C) {
  const int K = 1024, NT = 16;
  int wg = blockIdx.x;
  int nid = (wg & 7) * 64 + (wg >> 3);      // XCD-chunked, nwg=512 (%8==0)
  int m0 = (nid >> 2) * 256, n0 = (nid & 3) * 256;
  int t = threadIdx.x, wid = t >> 6, l = t & 63, lo = l & 15, hi = l >> 4;
  int wr = wid >> 2, wc = wid & 3;
  __shared__ alignas(16) ushort AS[2][256 * 64];
  __shared__ alignas(16) ushort BS[2][256 * 64];
  f32x4 acc[8][4];
  f32x4 zf = {0.f, 0.f, 0.f, 0.f};
#pragma unroll
  for (int i = 0; i < 8; i++)
#pragma unroll
    for (int j = 0; j < 4; j++) acc[i][j] = zf;
  int tr = t >> 3, tc = t & 7;
  int tcs = tc ^ (tr & 7);                  // T2: pre-swizzled source chunk
  const float*  gA = A  + (size_t)(m0 + tr) * K + tcs * 8;
  const ushort* gB = Bw + (size_t)(n0 + tr) * K + tcs * 8;
  float4 av[4][2];
  // ---- prologue: stage tile 0 ----
#pragma unroll
  for (int s = 0; s < 4; s++) {
    av[s][0] = *reinterpret_cast<const float4*>(gA + (size_t)s * 64 * K);
    av[s][1] = *reinterpret_cast<const float4*>(gA + (size_t)s * 64 * K + 4);
  }
#pragma unroll
  for (int s = 0; s < 4; s++)
    GLD16(gB + (size_t)s * 64 * K, &BS[0][s * 4096 + wid * 512]);
#pragma unroll
  for (int s = 0; s < 4; s++)
    *reinterpret_cast<short8*>(&AS[0][(s * 64 + tr) * 64 + tc * 8]) = pack2(av[s][0], av[s][1]);
  asm volatile("s_waitcnt lgkmcnt(0)" ::: "memory");
  __builtin_amdgcn_s_barrier();
  FENCE_SCHED();
  int swz = (lo & 7) << 3;                  // T2 read XOR (ushort units)
  int cur = 0;
  for (int kt = 0; kt < NT; kt++) {
    // (a) issue next tile's loads: 8 reg A-loads + 4 B gload_lds per wave
    if (kt + 1 < NT) {
      const float*  gAk = gA + (kt + 1) * 64;
      const ushort* gBk = gB + (kt + 1) * 64;
#pragma unroll
      for (int s = 0; s < 4; s++) {
        av[s][0] = *reinterpret_cast<const float4*>(gAk + (size_t)s * 64 * K);
        av[s][1] = *reinterpret_cast<const float4*>(gAk + (size_t)s * 64 * K + 4);
      }
#pragma unroll
      for (int s = 0; s < 4; s++)
        GLD16(gBk + (size_t)s * 64 * K, &BS[cur ^ 1][s * 4096 + wid * 512]);
      asm volatile("s_waitcnt vmcnt(12)" ::: "memory");
    } else {
      asm volatile("s_waitcnt vmcnt(0)" ::: "memory");
    }
    __builtin_amdgcn_s_barrier();
    FENCE_SCHED();
    // (c) compute: 8 ds_read_b128 + 16 MFMA per phase, swizzled col offsets
    const ushort* sA = &AS[cur][0];
    const ushort* sB = &BS[cur][0];
#pragma unroll
    for (int kk = 0; kk < 2; kk++)
#pragma unroll
      for (int mh = 0; mh < 2; mh++) {
        int co = (hi * 8 + kk * 32) ^ swz;
        short8 af[4], bfr[4];
#pragma unroll
        for (int q = 0; q < 4; q++)
          af[q] = *reinterpret_cast<const short8*>(sA + (wr * 128 + (mh * 4 + q) * 16 + lo) * 64 + co);
#pragma unroll
        for (int n = 0; n < 4; n++)
          bfr[n] = *reinterpret_cast<const short8*>(sB + (wc * 64 + n * 16 + lo) * 64 + co);
        __builtin_amdgcn_s_setprio(1);
#pragma unroll
        for (int q = 0; q < 4; q++)
#pragma unroll
          for (int n = 0; n < 4; n++)
            acc[mh * 4 + q][n] =
                __builtin_amdgcn_mfma_f32_16x16x32_bf16(af[q], bfr[n], acc[mh * 4 + q][n], 0, 0, 0);
        __builtin_amdgcn_s_setprio(0);
      }
    // (d) write-late: cvt + ds_write next A tile (linear addr, pre-swz data)
    if (kt + 1 < NT) {
#pragma unroll
      for (int s = 0; s < 4; s++)
        *reinterpret_cast<short8*>(&AS[cur ^ 1][(s * 64 + tr) * 64 + tc * 8]) =
            pack2(av[s][0], av[s][1]);
    }
    asm volatile("s_waitcnt lgkmcnt(0)" ::: "memory");
    __builtin_amdgcn_s_barrier();
    FENCE_SCHED();
    cur ^= 1;
  }
  // epilogue: bf16 C
#pragma unroll
  for (int mi = 0; mi < 8; mi++)
#pragma unroll
    for (int n = 0; n < 4; n++)
#pragma unroll
      for (int j = 0; j < 4; j++) {
        int r = m0 + wr * 128 + mi * 16 + hi * 4 + j;
        int c = n0 + wc * 64 + n * 16 + lo;
        C[(size_t)r * 1024 + c] = f2b(acc[mi][n][j]);
      }
}

// --------------------------- 5) attention ----------------------------------
__global__ __launch_bounds__(256) void k_attn(const ushort* __restrict__ Q,
                                              const ushort* __restrict__ Kall,
                                              const ushort* __restrict__ Vt,
                                              ushort* __restrict__ O) {
  int q0 = blockIdx.x * 128, bh = blockIdx.y;
  int b = bh >> 4, h = bh & 15;
  int t = threadIdx.x, w = t >> 6, l = t & 63, lo = l & 15, hi = l >> 4;
  __shared__ alignas(16) ushort P[4][32 * 104];
  const ushort* Qb = Q + ((size_t)b * 4096 + q0 + w * 32) * 1024 + h * 64;
  short8 qf[2][2];
  for (int mi = 0; mi < 2; mi++)
    for (int ks = 0; ks < 2; ks++)
      qf[mi][ks] = *reinterpret_cast<const short8*>(Qb + (size_t)(mi * 16 + lo) * 1024 + ks * 32 + hi * 8);
  const ushort* Kb = Kall + (size_t)bh * 96 * 64;
  f32x4 s[2][6];
  f32x4 zf = {0.f, 0.f, 0.f, 0.f};
  for (int i = 0; i < 2; i++) for (int j = 0; j < 6; j++) s[i][j] = zf;
  for (int ni = 0; ni < 6; ni++)
    for (int ks = 0; ks < 2; ks++) {
      short8 kf = *reinterpret_cast<const short8*>(Kb + (ni * 16 + lo) * 64 + ks * 32 + hi * 8);
      for (int mi = 0; mi < 2; mi++)
        s[mi][ni] = __builtin_amdgcn_mfma_f32_16x16x32_bf16(qf[mi][ks], kf, s[mi][ni], 0, 0, 0);
    }
  const float SC = 0.125f * 1.44269504088896340736f;
  for (int mi = 0; mi < 2; mi++)
    for (int j = 0; j < 4; j++) {
      float pb[5];
      float mb = -1e30f;
      for (int ni = 0; ni < 5; ni++) {
        int c = ni * 16 + lo;
        float v = s[mi][ni][j] * SC;
        pb[ni] = v;
        if (c < 77) mb = fmaxf(mb, v);
      }
      mb = fmaxf(mb, __shfl_xor(mb, 1, 64));
      mb = fmaxf(mb, __shfl_xor(mb, 2, 64));
      mb = fmaxf(mb, __shfl_xor(mb, 4, 64));
      mb = fmaxf(mb, __shfl_xor(mb, 8, 64));
      float sb = 0.f;
      for (int ni = 0; ni < 5; ni++) {
        int c = ni * 16 + lo;
        float p = (c < 77) ? exp2f(pb[ni] - mb) : 0.f;
        pb[ni] = p; sb += p;
      }
      sb += __shfl_xor(sb, 1, 64); sb += __shfl_xor(sb, 2, 64);
      sb += __shfl_xor(sb, 4, 64); sb += __shfl_xor(sb, 8, 64);
      float rb = 1.0f / sb;
      float vip = s[mi][5][j] * SC;
      bool val = lo < 4;
      float mip = val ? vip : -1e30f;
      mip = fmaxf(mip, __shfl_xor(mip, 1, 64));
      mip = fmaxf(mip, __shfl_xor(mip, 2, 64));
      mip = fmaxf(mip, __shfl_xor(mip, 4, 64));
      mip = fmaxf(mip, __shfl_xor(mip, 8, 64));
      float pi = val ? exp2f(vip - mip) : 0.f;
      float si = pi;
      si += __shfl_xor(si, 1, 64); si += __shfl_xor(si, 2, 64);
      si += __shfl_xor(si, 4, 64); si += __shfl_xor(si, 8, 64);
      float ri = 1.0f / si;
      int row = mi * 16 + hi * 4 + j;
      ushort* pr = &P[w][row * 104];
      for (int ni = 0; ni < 5; ni++) pr[ni * 16 + lo] = f2b(pb[ni] * rb);
      pr[80 + lo] = f2b(pi * ri);
    }
  __syncthreads();
  f32x4 o[2][4];
  for (int i = 0; i < 2; i++) for (int j = 0; j < 4; j++) o[i][j] = zf;
  const ushort* Vb = Vt + (size_t)bh * 64 * 96;
  for (int kk = 0; kk < 3; kk++) {
    short8 pf[2];
    for (int mi = 0; mi < 2; mi++)
      pf[mi] = *reinterpret_cast<const short8*>(&P[w][(mi * 16 + lo) * 104 + kk * 32 + hi * 8]);
    for (int dn = 0; dn < 4; dn++) {
      short8 vf = *reinterpret_cast<const short8*>(Vb + (dn * 16 + lo) * 96 + kk * 32 + hi * 8);
      for (int mi = 0; mi < 2; mi++)
        o[mi][dn] = __builtin_amdgcn_mfma_f32_16x16x32_bf16(pf[mi], vf, o[mi][dn], 0, 0, 0);
    }
  }
  ushort* Ob = O + ((size_t)b * 4096 + q0 + w * 32) * 1024 + h * 64;
  for (int mi = 0; mi < 2; mi++)
    for (int dn = 0; dn < 4; dn++)
      for (int j = 0; j < 4; j++)
        Ob[(size_t)(mi * 16 + hi * 4 + j) * 1024 + dn * 16 + lo] = f2b(o[mi][dn][j]);
}

// --------------------------- 6) output GEMM + bias -------------------------
__global__ __launch_bounds__(512, 2) void k_ogemm(const ushort* __restrict__ A,
                                                  const ushort* __restrict__ Bw,
                                                  const float* __restrict__ bias,
                                                  float* __restrict__ C) {
  const int K = 1024, NT = 16;
  int wg = blockIdx.x;
  int nid = (wg & 7) * 64 + (wg >> 3);
  int m0 = (nid >> 2) * 256, n0 = (nid & 3) * 256;
  int t = threadIdx.x, wid = t >> 6, l = t & 63, lo = l & 15, hi = l >> 4;
  int wr = wid >> 2, wc = wid & 3;
  __shared__ alignas(16) ushort AS[2][256 * 64];
  __shared__ alignas(16) ushort BS[2][256 * 64];
  f32x4 acc[8][4];
  f32x4 zf = {0.f, 0.f, 0.f, 0.f};
#pragma unroll
  for (int i = 0; i < 8; i++)
#pragma unroll
    for (int j = 0; j < 4; j++) acc[i][j] = zf;
  int tr = t >> 3, tc = t & 7;
  int tcs = tc ^ (tr & 7);                  // T2 pre-swizzled source chunk
  const ushort* gA = A  + (size_t)(m0 + tr) * K + tcs * 8;
  const ushort* gB = Bw + (size_t)(n0 + tr) * K + tcs * 8;
  // prologue: stage tile 0
#pragma unroll
  for (int s = 0; s < 4; s++)
    GLD16(gA + (size_t)s * 64 * K, &AS[0][s * 4096 + wid * 512]);
#pragma unroll
  for (int s = 0; s < 4; s++)
    GLD16(gB + (size_t)s * 64 * K, &BS[0][s * 4096 + wid * 512]);
  int swz = (lo & 7) << 3;
  int cur = 0;
  for (int kt = 0; kt < NT; kt++) {
    if (kt + 1 < NT) {
      const ushort* gAk = gA + (kt + 1) * 64;
      const ushort* gBk = gB + (kt + 1) * 64;
#pragma unroll
      for (int s = 0; s < 4; s++)
        GLD16(gAk + (size_t)s * 64 * K, &AS[cur ^ 1][s * 4096 + wid * 512]);
#pragma unroll
      for (int s = 0; s < 4; s++)
        GLD16(gBk + (size_t)s * 64 * K, &BS[cur ^ 1][s * 4096 + wid * 512]);
      asm volatile("s_waitcnt vmcnt(8)" ::: "memory");
    } else {
      asm volatile("s_waitcnt vmcnt(0)" ::: "memory");
    }
    __builtin_amdgcn_s_barrier();
    FENCE_SCHED();
    const ushort* sA = &AS[cur][0];
    const ushort* sB = &BS[cur][0];
#pragma unroll
    for (int kk = 0; kk < 2; kk++)
#pragma unroll
      for (int mh = 0; mh < 2; mh++) {
        int co = (hi * 8 + kk * 32) ^ swz;
        short8 af[4], bfr[4];
#pragma unroll
        for (int q = 0; q < 4; q++)
          af[q] = *reinterpret_cast<const short8*>(sA + (wr * 128 + (mh * 4 + q) * 16 + lo) * 64 + co);
#pragma unroll
        for (int n = 0; n < 4; n++)
          bfr[n] = *reinterpret_cast<const short8*>(sB + (wc * 64 + n * 16 + lo) * 64 + co);
        __builtin_amdgcn_s_setprio(1);
#pragma unroll
        for (int q = 0; q < 4; q++)
#pragma unroll
          for (int n = 0; n < 4; n++)
            acc[mh * 4 + q][n] =
                __builtin_amdgcn_mfma_f32_16x16x32_bf16(af[q], bfr[n], acc[mh * 4 + q][n], 0, 0, 0);
        __builtin_amdgcn_s_setprio(0);
      }
    asm volatile("s_waitcnt lgkmcnt(0)" ::: "memory");
    __builtin_amdgcn_s_barrier();
    FENCE_SCHED();
    cur ^= 1;
  }
#pragma unroll
  for (int n = 0; n < 4; n++) {
    int c = n0 + wc * 64 + n * 16 + lo;
    float bv = bias[c];
#pragma unroll
    for (int mi = 0; mi < 8; mi++)
#pragma unroll
      for (int j = 0; j < 4; j++) {
        int r = m0 + wr * 128 + mi * 16 + hi * 4 + j;
        C[(size_t)r * 1024 + c] = acc[mi][n][j] + bv;
      }
  }
}

// ---------------------------------------------------------------------------
extern "C" void kernel_launch(void* const* d_in, const int* in_sizes, int n_in,
                              void* d_out, int out_size, void* d_ws, size_t ws_size,
                              hipStream_t stream) {
  const float* hs   = (const float*)d_in[0];
  const float* enc  = (const float*)d_in[1];
  const float* Wq   = (const float*)d_in[2];
  const float* Wk   = (const float*)d_in[3];
  const float* Wv   = (const float*)d_in[4];
  const float* Wkip = (const float*)d_in[5];
  const float* Wvip = (const float*)d_in[6];
  const float* Wo   = (const float*)d_in[7];
  const float* bo   = (const float*)d_in[8];
  const float* lnw  = (const float*)d_in[9];
  const float* lnb  = (const float*)d_in[10];
  float* out = (float*)d_out;
  ushort* Qbuf = (ushort*)d_out;  // bf16 Q parked in first 64MB of the 128MB output

  ushort* p = (ushort*)d_ws;
  ushort* attn    = p; p += (size_t)32768 * 1024;
  ushort* wq_bf   = p; p += (size_t)1024 * 1024;
  ushort* wo_bf   = p; p += (size_t)1024 * 1024;
  ushort* wk_bf   = p; p += (size_t)1024 * 768;
  ushort* wkip_bf = p; p += (size_t)1024 * 768;
  ushort* wv_bf   = p; p += (size_t)1024 * 768;
  ushort* wvip_bf = p; p += (size_t)1024 * 768;
  ushort* xn      = p; p += (size_t)8 * 96 * 768;
  ushort* kall    = p; p += (size_t)8 * 16 * 96 * 64;
  ushort* vtall   = p; p += (size_t)8 * 16 * 96 * 64;

  CvtArgs ca;
  ca.src[0] = Wq;   ca.dst[0] = wq_bf;   ca.n4[0] = 262144;
  ca.src[1] = Wo;   ca.dst[1] = wo_bf;   ca.n4[1] = 262144;
  ca.src[2] = Wk;   ca.dst[2] = wk_bf;   ca.n4[2] = 196608;
  ca.src[3] = Wkip; ca.dst[3] = wkip_bf; ca.n4[3] = 196608;
  ca.src[4] = Wv;   ca.dst[4] = wv_bf;   ca.n4[4] = 196608;
  ca.src[5] = Wvip; ca.dst[5] = wvip_bf; ca.n4[5] = 196608;
  k_cvt_all<<<dim3(1024, 6), 256, 0, stream>>>(ca);
  k_build_xn<<<dim3(96, 8), 256, 0, stream>>>(enc, lnw, lnb, xn);
  k_kv<<<dim3(4, 8), 256, 0, stream>>>(xn, wk_bf, wkip_bf, kall, 0);
  k_kv<<<dim3(4, 8), 256, 0, stream>>>(xn, wv_bf, wvip_bf, vtall, 1);
  k_qgemm<<<512, 512, 0, stream>>>(hs, wq_bf, Qbuf);
  k_attn<<<dim3(32, 128), 256, 0, stream>>>(Qbuf, kall, vtall, attn);
  k_ogemm<<<512, 512, 0, stream>>>(attn, wo_bf, bo, out);
}